// Round 9
// baseline (400.765 us; speedup 1.0000x reference)
//
#include <hip/hip_runtime.h>

#define HEADS 4
#define FEAT 128          // H*C = 4*32
#define NEG_SLOPE 0.2f
#define NPB 64            // nodes per GEMM block
#define KT 32             // K tile
#define SCAN_B 1024       // scan chunk

// ---------------- CSR build ----------------

__global__ void count_kernel(const int* __restrict__ dst, int* __restrict__ deg, int E) {
    int i = blockIdx.x * blockDim.x + threadIdx.x;
    int stride = gridDim.x * blockDim.x;
    for (; i < E; i += stride) atomicAdd(&deg[dst[i]], 1);
}

// hierarchical scan, phase 1: per-block inclusive scan (LDS Hillis-Steele) + block totals
__global__ __launch_bounds__(SCAN_B) void scan_local_kernel(
        const int* __restrict__ deg, int* __restrict__ scanout,
        int* __restrict__ blocksums, int n) {
    __shared__ int tile[SCAN_B];
    int t = threadIdx.x;
    int i = blockIdx.x * SCAN_B + t;
    int v = (i < n) ? deg[i] : 0;
    tile[t] = v;
    __syncthreads();
    for (int off = 1; off < SCAN_B; off <<= 1) {
        int u = (t >= off) ? tile[t - off] : 0;
        __syncthreads();
        tile[t] += u;
        __syncthreads();
    }
    if (i < n) scanout[i] = tile[t];
    if (t == SCAN_B - 1) blocksums[blockIdx.x] = tile[SCAN_B - 1];
}

// phase 2: one block converts blocksums to its exclusive scan (nb <= 1024)
__global__ __launch_bounds__(SCAN_B) void scan_sums_kernel(int* __restrict__ blocksums, int nb) {
    __shared__ int tile[SCAN_B];
    int t = threadIdx.x;
    int v = (t < nb) ? blocksums[t] : 0;
    tile[t] = v;
    __syncthreads();
    for (int off = 1; off < SCAN_B; off <<= 1) {
        int u = (t >= off) ? tile[t - off] : 0;
        __syncthreads();
        tile[t] += u;
        __syncthreads();
    }
    int ex = (t == 0) ? 0 : tile[t - 1];
    if (t < nb) blocksums[t] = ex;
}

// phase 3: offsets[i+1] = local_inclusive[i] + block_prefix; offsets[0] = 0
__global__ void scan_add_kernel(const int* __restrict__ scanout,
                                const int* __restrict__ blocksums,
                                int* __restrict__ offsets, int n) {
    int i = blockIdx.x * blockDim.x + threadIdx.x;
    if (i < n) offsets[i + 1] = scanout[i] + blocksums[i >> 10];
    if (i == 0) offsets[0] = 0;
}

__global__ void scatter_kernel(const int* __restrict__ src, const int* __restrict__ dst,
                               const int* __restrict__ offsets, int* __restrict__ cursor,
                               int* __restrict__ col, int E) {
    int i = blockIdx.x * blockDim.x + threadIdx.x;
    int stride = gridDim.x * blockDim.x;
    for (; i < E; i += stride) {
        int d = dst[i];
        int pos = atomicAdd(&cursor[d], 1);
        col[offsets[d] + pos] = src[i];
    }
}

// ---------------- fused GEMM (h = x@W) + per-node attention coefficients ----------------
// v2: 128 threads, 64-node tile, acc[8 nodes][8 feats] per thread.
// Reuse doubled both ways vs v1: 16 ds_read_b128 per 256 FMA (0.0625 reads/FMA)
// -> LDS-throughput bound halved. thread t: fgrp=t&15 (f0=fgrp*8), ngrp=t>>4 (8 nodes).

__device__ __forceinline__ void fma4(float4& a, float s, const float4& b) {
    a.x += s * b.x; a.y += s * b.y; a.z += s * b.z; a.w += s * b.w;
}

__global__ __launch_bounds__(128) void gemm_alpha_kernel(
        const float* __restrict__ x, const float* __restrict__ W,
        const float* __restrict__ a_src, const float* __restrict__ a_dst,
        float* __restrict__ h, float* __restrict__ asrc_n,
        float* __restrict__ adst_n, int n_nodes) {
    __shared__ float xs[NPB][KT + 4];   // 36-float rows: 144B stride, 16B-aligned
    __shared__ float Ws[KT][FEAT];

    int t = threadIdx.x;
    int fgrp = t & 15;
    int f0 = fgrp * 8;          // 8 feats, all inside one head (8 | 32)
    int ngrp = t >> 4;          // 0..7 -> 8 nodes
    int n0 = blockIdx.x * NPB;

    float4 accA[8], accB[8];
    #pragma unroll
    for (int i = 0; i < 8; ++i) {
        accA[i] = make_float4(0.f, 0.f, 0.f, 0.f);
        accB[i] = make_float4(0.f, 0.f, 0.f, 0.f);
    }

    for (int kt = 0; kt < FEAT; kt += KT) {
        // stage x tile: 64 rows x 32 floats = 512 float4; 4 per thread
        #pragma unroll
        for (int r = 0; r < 4; ++r) {
            int idx = t + r * 128;
            int row = idx >> 3, q = idx & 7;
            float4 v = make_float4(0.f, 0.f, 0.f, 0.f);
            if (n0 + row < n_nodes)
                v = *(const float4*)&x[(size_t)(n0 + row) * FEAT + kt + q * 4];
            *(float4*)&xs[row][q * 4] = v;
        }
        // stage W tile: 32x128 = 1024 float4; 8 per thread
        #pragma unroll
        for (int r = 0; r < 8; ++r) {
            int idx = t + r * 128;
            int row = idx >> 5, c4 = idx & 31;
            *(float4*)&Ws[row][c4 * 4] =
                *(const float4*)&W[(size_t)(kt + row) * FEAT + c4 * 4];
        }
        __syncthreads();

        #pragma unroll
        for (int kk = 0; kk < KT; kk += 4) {
            float4 wA[4], wB[4];
            #pragma unroll
            for (int k = 0; k < 4; ++k) {
                wA[k] = *(const float4*)&Ws[kk + k][f0];
                wB[k] = *(const float4*)&Ws[kk + k][f0 + 4];
            }
            #pragma unroll
            for (int i = 0; i < 8; ++i) {
                float4 xv = *(const float4*)&xs[ngrp * 8 + i][kk];
                fma4(accA[i], xv.x, wA[0]); fma4(accA[i], xv.y, wA[1]);
                fma4(accA[i], xv.z, wA[2]); fma4(accA[i], xv.w, wA[3]);
                fma4(accB[i], xv.x, wB[0]); fma4(accB[i], xv.y, wB[1]);
                fma4(accB[i], xv.z, wB[2]); fma4(accB[i], xv.w, wB[3]);
            }
        }
        __syncthreads();
    }

    // epilogue: h stores + per-(node,head) attention coefficients
    float4 asA = *(const float4*)&a_src[f0];
    float4 asB = *(const float4*)&a_src[f0 + 4];
    float4 adA = *(const float4*)&a_dst[f0];
    float4 adB = *(const float4*)&a_dst[f0 + 4];
    int head = fgrp >> 2;       // f0>>5

    #pragma unroll
    for (int i = 0; i < 8; ++i) {
        int n = n0 + ngrp * 8 + i;
        bool ok = (n < n_nodes);
        if (ok) {
            *(float4*)&h[(size_t)n * FEAT + f0] = accA[i];
            *(float4*)&h[(size_t)n * FEAT + f0 + 4] = accB[i];
        }
        float ps = accA[i].x * asA.x + accA[i].y * asA.y + accA[i].z * asA.z + accA[i].w * asA.w
                 + accB[i].x * asB.x + accB[i].y * asB.y + accB[i].z * asB.z + accB[i].w * asB.w;
        float pd = accA[i].x * adA.x + accA[i].y * adA.y + accA[i].z * adA.z + accA[i].w * adA.w
                 + accB[i].x * adB.x + accB[i].y * adB.y + accB[i].z * adB.z + accB[i].w * adB.w;
        // reduce across the 4 threads (fgrp xor 1,2) sharing this (node, head)
        ps += __shfl_xor(ps, 1, 64); ps += __shfl_xor(ps, 2, 64);
        pd += __shfl_xor(pd, 1, 64); pd += __shfl_xor(pd, 2, 64);
        if (ok && (t & 3) == 0) {
            asrc_n[n * HEADS + head] = ps;
            adst_n[n * HEADS + head] = pd;
        }
    }
}

// ---------------- per-destination-node softmax aggregation ----------------
// 256 threads = 4 waves; one wave per node; lane handles feats {2*lane, 2*lane+1}.
// Single-pass softmax (shift-invariant; clamp exp arg at 60 for safety).
// Chunk-of-8 batched gathers: 8 col loads, then 8 asrc + 8 h-rows issue together
// (deeper memory-level parallelism toward the HBM floor).

__global__ __launch_bounds__(256) void aggregate_kernel(
        const float* __restrict__ h, const int* __restrict__ offsets,
        const int* __restrict__ col, const float* __restrict__ asrc_n,
        const float* __restrict__ adst_n, const float* __restrict__ bias,
        float* __restrict__ out, int n_nodes) {
    int wave = threadIdx.x >> 6;
    int lane = threadIdx.x & 63;
    int n = blockIdx.x * 4 + wave;
    if (n >= n_nodes) return;

    int head = lane >> 4;
    int beg = offsets[n];
    int end = offsets[n + 1];
    float ad = adst_n[n * HEADS + head];

    // self-loop folded into accumulator init
    float e_self = asrc_n[n * HEADS + head] + ad;
    e_self = e_self > 0.f ? e_self : NEG_SLOPE * e_self;
    float p = __expf(fminf(e_self, 60.f));
    float l = p;
    float2 hv = *(const float2*)&h[(size_t)n * FEAT + 2 * lane];
    float2 acc = make_float2(p * hv.x, p * hv.y);

    int j = beg;
    for (; j + 7 < end; j += 8) {
        int s[8];
        #pragma unroll
        for (int q = 0; q < 8; ++q) s[q] = col[j + q];
        float a[8];
        #pragma unroll
        for (int q = 0; q < 8; ++q) a[q] = asrc_n[s[q] * HEADS + head];
        float2 hr[8];
        #pragma unroll
        for (int q = 0; q < 8; ++q) hr[q] = *(const float2*)&h[(size_t)s[q] * FEAT + 2 * lane];
        #pragma unroll
        for (int q = 0; q < 8; ++q) {
            float e = a[q] + ad;
            e = e > 0.f ? e : NEG_SLOPE * e;
            float pe = __expf(fminf(e, 60.f));
            l += pe;
            acc.x += pe * hr[q].x;
            acc.y += pe * hr[q].y;
        }
    }
    for (; j + 3 < end; j += 4) {
        int s[4];
        #pragma unroll
        for (int q = 0; q < 4; ++q) s[q] = col[j + q];
        float a[4];
        #pragma unroll
        for (int q = 0; q < 4; ++q) a[q] = asrc_n[s[q] * HEADS + head];
        float2 hr[4];
        #pragma unroll
        for (int q = 0; q < 4; ++q) hr[q] = *(const float2*)&h[(size_t)s[q] * FEAT + 2 * lane];
        #pragma unroll
        for (int q = 0; q < 4; ++q) {
            float e = a[q] + ad;
            e = e > 0.f ? e : NEG_SLOPE * e;
            float pe = __expf(fminf(e, 60.f));
            l += pe;
            acc.x += pe * hr[q].x;
            acc.y += pe * hr[q].y;
        }
    }
    for (; j < end; ++j) {
        int s = col[j];
        float a = asrc_n[s * HEADS + head];
        float2 hs = *(const float2*)&h[(size_t)s * FEAT + 2 * lane];
        float e = a + ad;
        e = e > 0.f ? e : NEG_SLOPE * e;
        float pe = __expf(fminf(e, 60.f));
        l += pe;
        acc.x += pe * hs.x;
        acc.y += pe * hs.y;
    }

    float inv = 1.f / l;
    float2 bv = *(const float2*)&bias[2 * lane];
    float ox = acc.x * inv + bv.x;
    float oy = acc.y * inv + bv.y;
    float2 o = make_float2(ox > 0.f ? ox : 0.f, oy > 0.f ? oy : 0.f);
    *(float2*)&out[(size_t)n * FEAT + 2 * lane] = o;
}

// ---------------- launch ----------------

static inline size_t align_up(size_t v, size_t a) { return (v + a - 1) & ~(a - 1); }

extern "C" void kernel_launch(void* const* d_in, const int* in_sizes, int n_in,
                              void* d_out, int out_size, void* d_ws, size_t ws_size,
                              hipStream_t stream) {
    const float* x   = (const float*)d_in[0];
    const int*   ei  = (const int*)d_in[1];
    const float* W1  = (const float*)d_in[2];
    const float* as1 = (const float*)d_in[3];
    const float* ad1 = (const float*)d_in[4];
    const float* b1  = (const float*)d_in[5];
    const float* W2  = (const float*)d_in[6];
    const float* as2 = (const float*)d_in[7];
    const float* ad2 = (const float*)d_in[8];
    const float* b2  = (const float*)d_in[9];

    int N = in_sizes[0] / FEAT;
    int E = in_sizes[1] / 2;
    const int* src_idx = ei;
    const int* dst_idx = ei + E;

    int nsb = (N + SCAN_B - 1) / SCAN_B;

    char* p = (char*)d_ws;
    auto alloc = [&](size_t bytes) {
        char* r = p;
        p += align_up(bytes, 256);
        return r;
    };
    int*   deg      = (int*)alloc((size_t)N * 4);
    int*   offsets  = (int*)alloc((size_t)(N + 1) * 4);
    int*   cursor   = (int*)alloc((size_t)N * 4);
    int*   col      = (int*)alloc((size_t)E * 4);
    int*   scanout  = (int*)alloc((size_t)N * 4);
    int*   blocksum = (int*)alloc((size_t)nsb * 4);
    float* h        = (float*)alloc((size_t)N * FEAT * 4);
    float* asn      = (float*)alloc((size_t)N * HEADS * 4);
    float* adn      = (float*)alloc((size_t)N * HEADS * 4);
    float* buf1     = (float*)d_out;  // layer-1 output staged in d_out, overwritten by layer 2

    // CSR build (graph shared by both layers)
    hipMemsetAsync(deg, 0, (size_t)N * 4, stream);
    hipMemsetAsync(cursor, 0, (size_t)N * 4, stream);
    count_kernel<<<1024, 256, 0, stream>>>(dst_idx, deg, E);
    scan_local_kernel<<<nsb, SCAN_B, 0, stream>>>(deg, scanout, blocksum, N);
    scan_sums_kernel<<<1, SCAN_B, 0, stream>>>(blocksum, nsb);
    scan_add_kernel<<<(N + 255) / 256, 256, 0, stream>>>(scanout, blocksum, offsets, N);
    scatter_kernel<<<1024, 256, 0, stream>>>(src_idx, dst_idx, offsets, cursor, col, E);

    int gemm_grid = (N + NPB - 1) / NPB;
    int agg_grid = (N + 3) / 4;

    // layer 1
    gemm_alpha_kernel<<<gemm_grid, 128, 0, stream>>>(x, W1, as1, ad1, h, asn, adn, N);
    aggregate_kernel<<<agg_grid, 256, 0, stream>>>(h, offsets, col, asn, adn, b1, buf1, N);

    // layer 2 (input = buf1 in d_out; final output overwrites d_out)
    gemm_alpha_kernel<<<gemm_grid, 128, 0, stream>>>(buf1, W2, as2, ad2, h, asn, adn, N);
    aggregate_kernel<<<agg_grid, 256, 0, stream>>>(h, offsets, col, asn, adn, b2, (float*)d_out, N);
}

// Round 10
// 390.211 us; speedup vs baseline: 1.0270x; 1.0270x over previous
//
#include <hip/hip_runtime.h>

#define HEADS 4
#define FEAT 128          // H*C = 4*32
#define NEG_SLOPE 0.2f
#define NPB 32            // nodes per GEMM block (v1: 256 thr, 24 waves/CU — best measured)
#define KT 32             // K tile
#define SCAN_B 1024       // scan chunk

// ---------------- CSR build ----------------

__global__ void count_kernel(const int* __restrict__ dst, int* __restrict__ deg, int E) {
    int i = blockIdx.x * blockDim.x + threadIdx.x;
    int stride = gridDim.x * blockDim.x;
    for (; i < E; i += stride) atomicAdd(&deg[dst[i]], 1);
}

// hierarchical scan, phase 1: per-block inclusive scan (LDS Hillis-Steele) + block totals
__global__ __launch_bounds__(SCAN_B) void scan_local_kernel(
        const int* __restrict__ deg, int* __restrict__ scanout,
        int* __restrict__ blocksums, int n) {
    __shared__ int tile[SCAN_B];
    int t = threadIdx.x;
    int i = blockIdx.x * SCAN_B + t;
    int v = (i < n) ? deg[i] : 0;
    tile[t] = v;
    __syncthreads();
    for (int off = 1; off < SCAN_B; off <<= 1) {
        int u = (t >= off) ? tile[t - off] : 0;
        __syncthreads();
        tile[t] += u;
        __syncthreads();
    }
    if (i < n) scanout[i] = tile[t];
    if (t == SCAN_B - 1) blocksums[blockIdx.x] = tile[SCAN_B - 1];
}

// phase 2: one block converts blocksums to its exclusive scan (nb <= 1024)
__global__ __launch_bounds__(SCAN_B) void scan_sums_kernel(int* __restrict__ blocksums, int nb) {
    __shared__ int tile[SCAN_B];
    int t = threadIdx.x;
    int v = (t < nb) ? blocksums[t] : 0;
    tile[t] = v;
    __syncthreads();
    for (int off = 1; off < SCAN_B; off <<= 1) {
        int u = (t >= off) ? tile[t - off] : 0;
        __syncthreads();
        tile[t] += u;
        __syncthreads();
    }
    int ex = (t == 0) ? 0 : tile[t - 1];
    if (t < nb) blocksums[t] = ex;
}

// phase 3: offsets[i+1] = local_inclusive[i] + block_prefix; offsets[0] = 0
__global__ void scan_add_kernel(const int* __restrict__ scanout,
                                const int* __restrict__ blocksums,
                                int* __restrict__ offsets, int n) {
    int i = blockIdx.x * blockDim.x + threadIdx.x;
    if (i < n) offsets[i + 1] = scanout[i] + blocksums[i >> 10];
    if (i == 0) offsets[0] = 0;
}

// cursor pre-initialized to offsets (d2d copy) -> atomicAdd gives absolute position,
// no offsets[d] read per edge
__global__ void scatter_kernel(const int* __restrict__ src, const int* __restrict__ dst,
                               int* __restrict__ cursor, int* __restrict__ col, int E) {
    int i = blockIdx.x * blockDim.x + threadIdx.x;
    int stride = gridDim.x * blockDim.x;
    for (; i < E; i += stride) {
        int pos = atomicAdd(&cursor[dst[i]], 1);
        col[pos] = src[i];
    }
}

// ---------------- fused GEMM (h = x@W) + per-node attention coefficients ----------------
// v1 (best measured): 256 threads, NPB=32 nodes/block. thread t: fgrp=(t&31) -> f0=fgrp*4;
// ngrp=(t>>5) -> 4 nodes. Stage W[32x128] + x[32x32] in LDS; acc[4][4] in regs.

__global__ __launch_bounds__(256) void gemm_alpha_kernel(
        const float* __restrict__ x, const float* __restrict__ W,
        const float* __restrict__ a_src, const float* __restrict__ a_dst,
        float* __restrict__ h, float* __restrict__ asrc_n,
        float* __restrict__ adst_n, int n_nodes) {
    __shared__ float xs[NPB][KT + 4];   // +4 pad: row stride 144B keeps 16B align, breaks bank stride
    __shared__ float Ws[KT][FEAT];      // linear, conflict-free for row-linear b128 access

    int t = threadIdx.x;
    int fgrp = t & 31;
    int f0 = fgrp * 4;
    int ngrp = t >> 5;          // 0..7
    int n0 = blockIdx.x * NPB;

    float acc[4][4];
    #pragma unroll
    for (int i = 0; i < 4; ++i)
        #pragma unroll
        for (int j = 0; j < 4; ++j) acc[i][j] = 0.f;

    for (int kt = 0; kt < FEAT; kt += KT) {
        // stage x tile: thread t -> node=t>>3 (0..31), q=t&7 (8 float4 per 32-float row)
        {
            int node = t >> 3, q = t & 7;
            float4 v = make_float4(0.f, 0.f, 0.f, 0.f);
            if (n0 + node < n_nodes)
                v = *(const float4*)&x[(size_t)(n0 + node) * FEAT + kt + q * 4];
            *(float4*)&xs[node][q * 4] = v;
        }
        // stage W tile: 32x128 floats = 1024 float4; 4 per thread
        #pragma unroll
        for (int r = 0; r < 4; ++r) {
            int idx = t + r * 256;
            int row = idx >> 5, col4 = idx & 31;
            *(float4*)&Ws[row][col4 * 4] =
                *(const float4*)&W[(size_t)(kt + row) * FEAT + col4 * 4];
        }
        __syncthreads();

        #pragma unroll
        for (int kk = 0; kk < KT; kk += 4) {
            float4 w0 = *(const float4*)&Ws[kk + 0][f0];
            float4 w1 = *(const float4*)&Ws[kk + 1][f0];
            float4 w2 = *(const float4*)&Ws[kk + 2][f0];
            float4 w3 = *(const float4*)&Ws[kk + 3][f0];
            #pragma unroll
            for (int i = 0; i < 4; ++i) {
                float4 xv = *(const float4*)&xs[ngrp * 4 + i][kk];
                acc[i][0] += xv.x * w0.x + xv.y * w1.x + xv.z * w2.x + xv.w * w3.x;
                acc[i][1] += xv.x * w0.y + xv.y * w1.y + xv.z * w2.y + xv.w * w3.y;
                acc[i][2] += xv.x * w0.z + xv.y * w1.z + xv.z * w2.z + xv.w * w3.z;
                acc[i][3] += xv.x * w0.w + xv.y * w1.w + xv.z * w2.w + xv.w * w3.w;
            }
        }
        __syncthreads();
    }

    // write h (float4 per node) + attention coefficients
    float4 as4 = *(const float4*)&a_src[f0];
    float4 ad4 = *(const float4*)&a_dst[f0];
    int head = fgrp >> 3;       // f0>>5

    #pragma unroll
    for (int i = 0; i < 4; ++i) {
        int n = n0 + ngrp * 4 + i;
        bool ok = (n < n_nodes);
        if (ok)
            *(float4*)&h[(size_t)n * FEAT + f0] =
                make_float4(acc[i][0], acc[i][1], acc[i][2], acc[i][3]);

        float ps = acc[i][0] * as4.x + acc[i][1] * as4.y + acc[i][2] * as4.z + acc[i][3] * as4.w;
        float pd = acc[i][0] * ad4.x + acc[i][1] * ad4.y + acc[i][2] * ad4.z + acc[i][3] * ad4.w;
        // reduce across the 8 lanes (xor 1,2,4) sharing this (node, head)
        #pragma unroll
        for (int m = 4; m >= 1; m >>= 1) {
            ps += __shfl_xor(ps, m, 64);
            pd += __shfl_xor(pd, m, 64);
        }
        if (ok && (t & 7) == 0) {
            asrc_n[n * HEADS + head] = ps;
            adst_n[n * HEADS + head] = pd;
        }
    }
}

// ---------------- per-destination-node softmax aggregation ----------------
// 256 threads = 4 waves; one wave per node; lane handles feats {2*lane, 2*lane+1}.
// Single-pass softmax; chunk-of-8 batched gathers for MLP.
// All gather offsets are int32 (max 50000*128 = 6.4M << 2^31): avoids per-edge
// 64-bit mul/carry address chains that dominated VALU at R9.

__global__ __launch_bounds__(256) void aggregate_kernel(
        const float* __restrict__ h, const int* __restrict__ offsets,
        const int* __restrict__ col, const float* __restrict__ asrc_n,
        const float* __restrict__ adst_n, const float* __restrict__ bias,
        float* __restrict__ out, int n_nodes) {
    int wave = threadIdx.x >> 6;
    int lane = threadIdx.x & 63;
    int n = blockIdx.x * 4 + wave;
    if (n >= n_nodes) return;

    int head = lane >> 4;
    int lane2 = 2 * lane;
    int beg = offsets[n];
    int end = offsets[n + 1];
    float ad = adst_n[n * HEADS + head];

    // self-loop folded into accumulator init
    float e_self = asrc_n[n * HEADS + head] + ad;
    e_self = e_self > 0.f ? e_self : NEG_SLOPE * e_self;
    float p = __expf(fminf(e_self, 60.f));
    float l = p;
    float2 hv = *(const float2*)&h[n * FEAT + lane2];
    float2 acc = make_float2(p * hv.x, p * hv.y);

    int j = beg;
    for (; j + 7 < end; j += 8) {
        int s[8];
        #pragma unroll
        for (int q = 0; q < 8; ++q) s[q] = col[j + q];
        float a[8];
        #pragma unroll
        for (int q = 0; q < 8; ++q) a[q] = asrc_n[s[q] * HEADS + head];
        float2 hr[8];
        #pragma unroll
        for (int q = 0; q < 8; ++q) hr[q] = *(const float2*)&h[s[q] * FEAT + lane2];
        #pragma unroll
        for (int q = 0; q < 8; ++q) {
            float e = a[q] + ad;
            e = e > 0.f ? e : NEG_SLOPE * e;
            float pe = __expf(fminf(e, 60.f));
            l += pe;
            acc.x += pe * hr[q].x;
            acc.y += pe * hr[q].y;
        }
    }
    for (; j + 3 < end; j += 4) {
        int s[4];
        #pragma unroll
        for (int q = 0; q < 4; ++q) s[q] = col[j + q];
        float a[4];
        #pragma unroll
        for (int q = 0; q < 4; ++q) a[q] = asrc_n[s[q] * HEADS + head];
        float2 hr[4];
        #pragma unroll
        for (int q = 0; q < 4; ++q) hr[q] = *(const float2*)&h[s[q] * FEAT + lane2];
        #pragma unroll
        for (int q = 0; q < 4; ++q) {
            float e = a[q] + ad;
            e = e > 0.f ? e : NEG_SLOPE * e;
            float pe = __expf(fminf(e, 60.f));
            l += pe;
            acc.x += pe * hr[q].x;
            acc.y += pe * hr[q].y;
        }
    }
    for (; j < end; ++j) {
        int s = col[j];
        float a = asrc_n[s * HEADS + head];
        float2 hs = *(const float2*)&h[s * FEAT + lane2];
        float e = a + ad;
        e = e > 0.f ? e : NEG_SLOPE * e;
        float pe = __expf(fminf(e, 60.f));
        l += pe;
        acc.x += pe * hs.x;
        acc.y += pe * hs.y;
    }

    float inv = 1.f / l;
    float2 bv = *(const float2*)&bias[lane2];
    float ox = acc.x * inv + bv.x;
    float oy = acc.y * inv + bv.y;
    float2 o = make_float2(ox > 0.f ? ox : 0.f, oy > 0.f ? oy : 0.f);
    *(float2*)&out[n * FEAT + lane2] = o;
}

// ---------------- launch ----------------

static inline size_t align_up(size_t v, size_t a) { return (v + a - 1) & ~(a - 1); }

extern "C" void kernel_launch(void* const* d_in, const int* in_sizes, int n_in,
                              void* d_out, int out_size, void* d_ws, size_t ws_size,
                              hipStream_t stream) {
    const float* x   = (const float*)d_in[0];
    const int*   ei  = (const int*)d_in[1];
    const float* W1  = (const float*)d_in[2];
    const float* as1 = (const float*)d_in[3];
    const float* ad1 = (const float*)d_in[4];
    const float* b1  = (const float*)d_in[5];
    const float* W2  = (const float*)d_in[6];
    const float* as2 = (const float*)d_in[7];
    const float* ad2 = (const float*)d_in[8];
    const float* b2  = (const float*)d_in[9];

    int N = in_sizes[0] / FEAT;
    int E = in_sizes[1] / 2;
    const int* src_idx = ei;
    const int* dst_idx = ei + E;

    int nsb = (N + SCAN_B - 1) / SCAN_B;

    char* p = (char*)d_ws;
    auto alloc = [&](size_t bytes) {
        char* r = p;
        p += align_up(bytes, 256);
        return r;
    };
    int*   deg      = (int*)alloc((size_t)N * 4);
    int*   offsets  = (int*)alloc((size_t)(N + 1) * 4);
    int*   cursor   = (int*)alloc((size_t)N * 4);
    int*   col      = (int*)alloc((size_t)E * 4);
    int*   scanout  = (int*)alloc((size_t)N * 4);
    int*   blocksum = (int*)alloc((size_t)nsb * 4);
    float* h        = (float*)alloc((size_t)N * FEAT * 4);
    float* asn      = (float*)alloc((size_t)N * HEADS * 4);
    float* adn      = (float*)alloc((size_t)N * HEADS * 4);
    float* buf1     = (float*)d_out;  // layer-1 output staged in d_out, overwritten by layer 2

    // CSR build (graph shared by both layers)
    hipMemsetAsync(deg, 0, (size_t)N * 4, stream);
    count_kernel<<<1024, 256, 0, stream>>>(dst_idx, deg, E);
    scan_local_kernel<<<nsb, SCAN_B, 0, stream>>>(deg, scanout, blocksum, N);
    scan_sums_kernel<<<1, SCAN_B, 0, stream>>>(blocksum, nsb);
    scan_add_kernel<<<(N + 255) / 256, 256, 0, stream>>>(scanout, blocksum, offsets, N);
    hipMemcpyAsync(cursor, offsets, (size_t)N * 4, hipMemcpyDeviceToDevice, stream);
    scatter_kernel<<<1024, 256, 0, stream>>>(src_idx, dst_idx, cursor, col, E);

    int gemm_grid = (N + NPB - 1) / NPB;
    int agg_grid = (N + 3) / 4;

    // layer 1
    gemm_alpha_kernel<<<gemm_grid, 256, 0, stream>>>(x, W1, as1, ad1, h, asn, adn, N);
    aggregate_kernel<<<agg_grid, 256, 0, stream>>>(h, offsets, col, asn, adn, b1, buf1, N);

    // layer 2 (input = buf1 in d_out; final output overwrites d_out)
    gemm_alpha_kernel<<<gemm_grid, 256, 0, stream>>>(buf1, W2, as2, ad2, h, asn, adn, N);
    aggregate_kernel<<<agg_grid, 256, 0, stream>>>(h, offsets, col, asn, adn, b2, (float*)d_out, N);
}

// Round 11
// 354.788 us; speedup vs baseline: 1.1296x; 1.0998x over previous
//
#include <hip/hip_runtime.h>
#include <hip/hip_fp16.h>

#define HEADS 4
#define FEAT 128          // H*C = 4*32
#define NEG_SLOPE 0.2f
#define NPB 32            // nodes per GEMM block (v1: 256 thr, 24 waves/CU — best measured)
#define KT 32             // K tile
#define SCAN_B 1024       // scan chunk

// ---------------- CSR build ----------------

__global__ void count_kernel(const int* __restrict__ dst, int* __restrict__ deg, int E) {
    int i = blockIdx.x * blockDim.x + threadIdx.x;
    int stride = gridDim.x * blockDim.x;
    for (; i < E; i += stride) atomicAdd(&deg[dst[i]], 1);
}

// hierarchical scan, phase 1: per-block inclusive scan (LDS Hillis-Steele) + block totals
__global__ __launch_bounds__(SCAN_B) void scan_local_kernel(
        const int* __restrict__ deg, int* __restrict__ scanout,
        int* __restrict__ blocksums, int n) {
    __shared__ int tile[SCAN_B];
    int t = threadIdx.x;
    int i = blockIdx.x * SCAN_B + t;
    int v = (i < n) ? deg[i] : 0;
    tile[t] = v;
    __syncthreads();
    for (int off = 1; off < SCAN_B; off <<= 1) {
        int u = (t >= off) ? tile[t - off] : 0;
        __syncthreads();
        tile[t] += u;
        __syncthreads();
    }
    if (i < n) scanout[i] = tile[t];
    if (t == SCAN_B - 1) blocksums[blockIdx.x] = tile[SCAN_B - 1];
}

// phase 2: one block converts blocksums to its exclusive scan (nb <= 1024)
__global__ __launch_bounds__(SCAN_B) void scan_sums_kernel(int* __restrict__ blocksums, int nb) {
    __shared__ int tile[SCAN_B];
    int t = threadIdx.x;
    int v = (t < nb) ? blocksums[t] : 0;
    tile[t] = v;
    __syncthreads();
    for (int off = 1; off < SCAN_B; off <<= 1) {
        int u = (t >= off) ? tile[t - off] : 0;
        __syncthreads();
        tile[t] += u;
        __syncthreads();
    }
    int ex = (t == 0) ? 0 : tile[t - 1];
    if (t < nb) blocksums[t] = ex;
}

// phase 3: offsets[i+1] = local_inclusive[i] + block_prefix; offsets[0] = 0
__global__ void scan_add_kernel(const int* __restrict__ scanout,
                                const int* __restrict__ blocksums,
                                int* __restrict__ offsets, int n) {
    int i = blockIdx.x * blockDim.x + threadIdx.x;
    if (i < n) offsets[i + 1] = scanout[i] + blocksums[i >> 10];
    if (i == 0) offsets[0] = 0;
}

// cursor pre-initialized to offsets (d2d copy) -> atomicAdd gives absolute position
__global__ void scatter_kernel(const int* __restrict__ src, const int* __restrict__ dst,
                               int* __restrict__ cursor, int* __restrict__ col, int E) {
    int i = blockIdx.x * blockDim.x + threadIdx.x;
    int stride = gridDim.x * blockDim.x;
    for (; i < E; i += stride) {
        int pos = atomicAdd(&cursor[dst[i]], 1);
        col[pos] = src[i];
    }
}

// ---------------- fused GEMM (h = x@W) + per-node attention coefficients ----------------
// v1 structure (best measured). h now stored as fp16: halves the aggregate gather's
// L2-request count and bytes; alpha coefficients still computed from fp32 accumulators.

__global__ __launch_bounds__(256) void gemm_alpha_kernel(
        const float* __restrict__ x, const float* __restrict__ W,
        const float* __restrict__ a_src, const float* __restrict__ a_dst,
        __half* __restrict__ h, float* __restrict__ asrc_n,
        float* __restrict__ adst_n, int n_nodes) {
    __shared__ float xs[NPB][KT + 4];   // +4 pad: row stride 144B keeps 16B align, breaks bank stride
    __shared__ float Ws[KT][FEAT];      // linear, conflict-free for row-linear b128 access

    int t = threadIdx.x;
    int fgrp = t & 31;
    int f0 = fgrp * 4;
    int ngrp = t >> 5;          // 0..7
    int n0 = blockIdx.x * NPB;

    float acc[4][4];
    #pragma unroll
    for (int i = 0; i < 4; ++i)
        #pragma unroll
        for (int j = 0; j < 4; ++j) acc[i][j] = 0.f;

    for (int kt = 0; kt < FEAT; kt += KT) {
        // stage x tile: thread t -> node=t>>3 (0..31), q=t&7 (8 float4 per 32-float row)
        {
            int node = t >> 3, q = t & 7;
            float4 v = make_float4(0.f, 0.f, 0.f, 0.f);
            if (n0 + node < n_nodes)
                v = *(const float4*)&x[(size_t)(n0 + node) * FEAT + kt + q * 4];
            *(float4*)&xs[node][q * 4] = v;
        }
        // stage W tile: 32x128 floats = 1024 float4; 4 per thread
        #pragma unroll
        for (int r = 0; r < 4; ++r) {
            int idx = t + r * 256;
            int row = idx >> 5, col4 = idx & 31;
            *(float4*)&Ws[row][col4 * 4] =
                *(const float4*)&W[(size_t)(kt + row) * FEAT + col4 * 4];
        }
        __syncthreads();

        #pragma unroll
        for (int kk = 0; kk < KT; kk += 4) {
            float4 w0 = *(const float4*)&Ws[kk + 0][f0];
            float4 w1 = *(const float4*)&Ws[kk + 1][f0];
            float4 w2 = *(const float4*)&Ws[kk + 2][f0];
            float4 w3 = *(const float4*)&Ws[kk + 3][f0];
            #pragma unroll
            for (int i = 0; i < 4; ++i) {
                float4 xv = *(const float4*)&xs[ngrp * 4 + i][kk];
                acc[i][0] += xv.x * w0.x + xv.y * w1.x + xv.z * w2.x + xv.w * w3.x;
                acc[i][1] += xv.x * w0.y + xv.y * w1.y + xv.z * w2.y + xv.w * w3.y;
                acc[i][2] += xv.x * w0.z + xv.y * w1.z + xv.z * w2.z + xv.w * w3.z;
                acc[i][3] += xv.x * w0.w + xv.y * w1.w + xv.z * w2.w + xv.w * w3.w;
            }
        }
        __syncthreads();
    }

    // write h (fp16, 8B per node) + attention coefficients (from fp32 accs)
    float4 as4 = *(const float4*)&a_src[f0];
    float4 ad4 = *(const float4*)&a_dst[f0];
    int head = fgrp >> 3;       // f0>>5

    #pragma unroll
    for (int i = 0; i < 4; ++i) {
        int n = n0 + ngrp * 4 + i;
        bool ok = (n < n_nodes);
        if (ok) {
            __half2 ha = __floats2half2_rn(acc[i][0], acc[i][1]);
            __half2 hb = __floats2half2_rn(acc[i][2], acc[i][3]);
            *(__half2*)&h[n * FEAT + f0] = ha;
            *(__half2*)&h[n * FEAT + f0 + 2] = hb;
        }

        float ps = acc[i][0] * as4.x + acc[i][1] * as4.y + acc[i][2] * as4.z + acc[i][3] * as4.w;
        float pd = acc[i][0] * ad4.x + acc[i][1] * ad4.y + acc[i][2] * ad4.z + acc[i][3] * ad4.w;
        // reduce across the 8 lanes (xor 1,2,4) sharing this (node, head)
        #pragma unroll
        for (int m = 4; m >= 1; m >>= 1) {
            ps += __shfl_xor(ps, m, 64);
            pd += __shfl_xor(pd, m, 64);
        }
        if (ok && (t & 7) == 0) {
            asrc_n[n * HEADS + head] = ps;
            adst_n[n * HEADS + head] = pd;
        }
    }
}

// ---------------- per-destination-node softmax aggregation ----------------
// 256 threads = 4 waves; one wave per node; lane handles feats {2*lane, 2*lane+1}.
// Single-pass softmax; chunk-of-8 batched gathers. h gathered as fp16 __half2 (4B/lane):
// 256B per row per wave = half the L2 cacheline requests of the fp32 version.

__global__ __launch_bounds__(256) void aggregate_kernel(
        const __half* __restrict__ h, const int* __restrict__ offsets,
        const int* __restrict__ col, const float* __restrict__ asrc_n,
        const float* __restrict__ adst_n, const float* __restrict__ bias,
        float* __restrict__ out, int n_nodes) {
    int wave = threadIdx.x >> 6;
    int lane = threadIdx.x & 63;
    int n = blockIdx.x * 4 + wave;
    if (n >= n_nodes) return;

    int head = lane >> 4;
    int lane2 = 2 * lane;
    int beg = offsets[n];
    int end = offsets[n + 1];
    float ad = adst_n[n * HEADS + head];

    // self-loop folded into accumulator init
    float e_self = asrc_n[n * HEADS + head] + ad;
    e_self = e_self > 0.f ? e_self : NEG_SLOPE * e_self;
    float p = __expf(fminf(e_self, 60.f));
    float l = p;
    float2 hv = __half22float2(*(const __half2*)&h[n * FEAT + lane2]);
    float2 acc = make_float2(p * hv.x, p * hv.y);

    int j = beg;
    for (; j + 7 < end; j += 8) {
        int s[8];
        #pragma unroll
        for (int q = 0; q < 8; ++q) s[q] = col[j + q];
        float a[8];
        #pragma unroll
        for (int q = 0; q < 8; ++q) a[q] = asrc_n[s[q] * HEADS + head];
        __half2 hr[8];
        #pragma unroll
        for (int q = 0; q < 8; ++q) hr[q] = *(const __half2*)&h[s[q] * FEAT + lane2];
        #pragma unroll
        for (int q = 0; q < 8; ++q) {
            float e = a[q] + ad;
            e = e > 0.f ? e : NEG_SLOPE * e;
            float pe = __expf(fminf(e, 60.f));
            float2 hf = __half22float2(hr[q]);
            l += pe;
            acc.x += pe * hf.x;
            acc.y += pe * hf.y;
        }
    }
    for (; j + 3 < end; j += 4) {
        int s[4];
        #pragma unroll
        for (int q = 0; q < 4; ++q) s[q] = col[j + q];
        float a[4];
        #pragma unroll
        for (int q = 0; q < 4; ++q) a[q] = asrc_n[s[q] * HEADS + head];
        __half2 hr[4];
        #pragma unroll
        for (int q = 0; q < 4; ++q) hr[q] = *(const __half2*)&h[s[q] * FEAT + lane2];
        #pragma unroll
        for (int q = 0; q < 4; ++q) {
            float e = a[q] + ad;
            e = e > 0.f ? e : NEG_SLOPE * e;
            float pe = __expf(fminf(e, 60.f));
            float2 hf = __half22float2(hr[q]);
            l += pe;
            acc.x += pe * hf.x;
            acc.y += pe * hf.y;
        }
    }
    for (; j < end; ++j) {
        int s = col[j];
        float a = asrc_n[s * HEADS + head];
        float2 hs = __half22float2(*(const __half2*)&h[s * FEAT + lane2]);
        float e = a + ad;
        e = e > 0.f ? e : NEG_SLOPE * e;
        float pe = __expf(fminf(e, 60.f));
        l += pe;
        acc.x += pe * hs.x;
        acc.y += pe * hs.y;
    }

    float inv = 1.f / l;
    float2 bv = *(const float2*)&bias[lane2];
    float ox = acc.x * inv + bv.x;
    float oy = acc.y * inv + bv.y;
    float2 o = make_float2(ox > 0.f ? ox : 0.f, oy > 0.f ? oy : 0.f);
    *(float2*)&out[n * FEAT + lane2] = o;
}

// ---------------- launch ----------------

static inline size_t align_up(size_t v, size_t a) { return (v + a - 1) & ~(a - 1); }

extern "C" void kernel_launch(void* const* d_in, const int* in_sizes, int n_in,
                              void* d_out, int out_size, void* d_ws, size_t ws_size,
                              hipStream_t stream) {
    const float* x   = (const float*)d_in[0];
    const int*   ei  = (const int*)d_in[1];
    const float* W1  = (const float*)d_in[2];
    const float* as1 = (const float*)d_in[3];
    const float* ad1 = (const float*)d_in[4];
    const float* b1  = (const float*)d_in[5];
    const float* W2  = (const float*)d_in[6];
    const float* as2 = (const float*)d_in[7];
    const float* ad2 = (const float*)d_in[8];
    const float* b2  = (const float*)d_in[9];

    int N = in_sizes[0] / FEAT;
    int E = in_sizes[1] / 2;
    const int* src_idx = ei;
    const int* dst_idx = ei + E;

    int nsb = (N + SCAN_B - 1) / SCAN_B;

    char* p = (char*)d_ws;
    auto alloc = [&](size_t bytes) {
        char* r = p;
        p += align_up(bytes, 256);
        return r;
    };
    int*    deg      = (int*)alloc((size_t)N * 4);
    int*    offsets  = (int*)alloc((size_t)(N + 1) * 4);
    int*    cursor   = (int*)alloc((size_t)N * 4);
    int*    col      = (int*)alloc((size_t)E * 4);
    int*    scanout  = (int*)alloc((size_t)N * 4);
    int*    blocksum = (int*)alloc((size_t)nsb * 4);
    __half* h        = (__half*)alloc((size_t)N * FEAT * 2);
    float*  asn      = (float*)alloc((size_t)N * HEADS * 4);
    float*  adn      = (float*)alloc((size_t)N * HEADS * 4);
    float*  buf1     = (float*)d_out;  // layer-1 output staged in d_out, overwritten by layer 2

    // CSR build (graph shared by both layers)
    hipMemsetAsync(deg, 0, (size_t)N * 4, stream);
    count_kernel<<<1024, 256, 0, stream>>>(dst_idx, deg, E);
    scan_local_kernel<<<nsb, SCAN_B, 0, stream>>>(deg, scanout, blocksum, N);
    scan_sums_kernel<<<1, SCAN_B, 0, stream>>>(blocksum, nsb);
    scan_add_kernel<<<(N + 255) / 256, 256, 0, stream>>>(scanout, blocksum, offsets, N);
    hipMemcpyAsync(cursor, offsets, (size_t)N * 4, hipMemcpyDeviceToDevice, stream);
    scatter_kernel<<<1024, 256, 0, stream>>>(src_idx, dst_idx, cursor, col, E);

    int gemm_grid = (N + NPB - 1) / NPB;
    int agg_grid = (N + 3) / 4;

    // layer 1
    gemm_alpha_kernel<<<gemm_grid, 256, 0, stream>>>(x, W1, as1, ad1, h, asn, adn, N);
    aggregate_kernel<<<agg_grid, 256, 0, stream>>>(h, offsets, col, asn, adn, b1, buf1, N);

    // layer 2 (input = buf1 in d_out; final output overwrites d_out)
    gemm_alpha_kernel<<<gemm_grid, 256, 0, stream>>>(buf1, W2, as2, ad2, h, asn, adn, N);
    aggregate_kernel<<<agg_grid, 256, 0, stream>>>(h, offsets, col, asn, adn, b2, (float*)d_out, N);
}

// Round 13
// 317.135 us; speedup vs baseline: 1.2637x; 1.1187x over previous
//
#include <hip/hip_runtime.h>
#include <hip/hip_fp16.h>

#define HEADS 4
#define FEAT 128          // H*C = 4*32
#define NEG_SLOPE 0.2f
#define SCAN_B 1024       // scan chunk
#define GPAD 136          // LDS row stride in halfs (128+8): 272B rows -> 2-way bank conflicts max

typedef _Float16 half8 __attribute__((ext_vector_type(8)));
typedef _Float16 half4v __attribute__((ext_vector_type(4)));
typedef float f32x4 __attribute__((ext_vector_type(4)));

// ---------------- CSR build ----------------

__global__ void count_kernel(const int* __restrict__ dst, int* __restrict__ deg, int E) {
    int i = blockIdx.x * blockDim.x + threadIdx.x;
    int stride = gridDim.x * blockDim.x;
    for (; i < E; i += stride) atomicAdd(&deg[dst[i]], 1);
}

__global__ __launch_bounds__(SCAN_B) void scan_local_kernel(
        const int* __restrict__ deg, int* __restrict__ scanout,
        int* __restrict__ blocksums, int n) {
    __shared__ int tile[SCAN_B];
    int t = threadIdx.x;
    int i = blockIdx.x * SCAN_B + t;
    int v = (i < n) ? deg[i] : 0;
    tile[t] = v;
    __syncthreads();
    for (int off = 1; off < SCAN_B; off <<= 1) {
        int u = (t >= off) ? tile[t - off] : 0;
        __syncthreads();
        tile[t] += u;
        __syncthreads();
    }
    if (i < n) scanout[i] = tile[t];
    if (t == SCAN_B - 1) blocksums[blockIdx.x] = tile[SCAN_B - 1];
}

__global__ __launch_bounds__(SCAN_B) void scan_sums_kernel(int* __restrict__ blocksums, int nb) {
    __shared__ int tile[SCAN_B];
    int t = threadIdx.x;
    int v = (t < nb) ? blocksums[t] : 0;
    tile[t] = v;
    __syncthreads();
    for (int off = 1; off < SCAN_B; off <<= 1) {
        int u = (t >= off) ? tile[t - off] : 0;
        __syncthreads();
        tile[t] += u;
        __syncthreads();
    }
    int ex = (t == 0) ? 0 : tile[t - 1];
    if (t < nb) blocksums[t] = ex;
}

__global__ void scan_add_kernel(const int* __restrict__ scanout,
                                const int* __restrict__ blocksums,
                                int* __restrict__ offsets, int n) {
    int i = blockIdx.x * blockDim.x + threadIdx.x;
    if (i < n) offsets[i + 1] = scanout[i] + blocksums[i >> 10];
    if (i == 0) offsets[0] = 0;
}

// cursor pre-initialized to offsets (d2d copy) -> atomicAdd gives absolute position
__global__ void scatter_kernel(const int* __restrict__ src, const int* __restrict__ dst,
                               int* __restrict__ cursor, int* __restrict__ col, int E) {
    int i = blockIdx.x * blockDim.x + threadIdx.x;
    int stride = gridDim.x * blockDim.x;
    for (; i < E; i += stride) {
        int pos = atomicAdd(&cursor[dst[i]], 1);
        col[pos] = src[i];
    }
}

// ---------------- W transpose + fp16 convert: wt[feat][k] = W[k][feat] ----------------
// 8 blocks x 256 threads; coalesced fp32 reads, scattered 2B writes (32KB total, trivial).

__global__ void wtrans_kernel(const float* __restrict__ W, __half* __restrict__ wt) {
    int t = threadIdx.x;
    #pragma unroll
    for (int i = 0; i < 8; ++i) {
        int flat = blockIdx.x * 2048 + i * 256 + t;   // 16384 elems
        int k = flat >> 7, f = flat & 127;
        wt[f * 128 + k] = __float2half(W[k * 128 + f]);
    }
}

// ---------------- MFMA GEMM (h = x@W, fp16 in / fp32 acc) + attention coefficients ----
// 256 thr = 4 waves; block tile 64 nodes x 128 feats; K=128 in 4 steps of 32.
// Stage x (fp32->fp16) and Wt (fp16) in LDS once; wave w computes nodes w*16..w*16+15
// as 8 MFMA tiles (16x16x32). D-layout (verified): col=lane&15, row=(lane>>4)*4+reg.
// A-frag: row=lane&15, k=(lane>>4)*8+j (contig 8 halfs). B-frag: col=lane&15 -> Wt row.

__global__ __launch_bounds__(256) void gemm_alpha_kernel(
        const float* __restrict__ x, const __half* __restrict__ wt,
        const float* __restrict__ a_src, const float* __restrict__ a_dst,
        __half* __restrict__ h, float* __restrict__ asrc_n,
        float* __restrict__ adst_n, int n_nodes) {
    __shared__ _Float16 xs[64 * GPAD];    // 17408 B
    __shared__ _Float16 ws[128 * GPAD];   // 34816 B

    int t = threadIdx.x;
    int n0 = blockIdx.x * 64;

    // stage x: 64 rows x 128 k (2048 float4 reads, 8 per thread)
    #pragma unroll
    for (int i = 0; i < 8; ++i) {
        int flat = t + i * 256;
        int row = flat >> 5, q = flat & 31;
        float4 v = make_float4(0.f, 0.f, 0.f, 0.f);
        if (n0 + row < n_nodes) v = *(const float4*)&x[(n0 + row) * FEAT + q * 4];
        half4v hv = { (_Float16)v.x, (_Float16)v.y, (_Float16)v.z, (_Float16)v.w };
        *(half4v*)&xs[row * GPAD + q * 4] = hv;   // 8B store, aligned (272|8, q*8|8)
    }
    // stage Wt: 128 rows x 128 k fp16 (2048 x 16B, 8 per thread)
    #pragma unroll
    for (int i = 0; i < 8; ++i) {
        int flat = t + i * 256;
        int row = flat >> 4, c = flat & 15;
        half8 v = *(const half8*)&wt[row * 128 + c * 8];
        *(half8*)&ws[row * GPAD + c * 8] = v;     // 16B store, aligned (272=17*16)
    }
    __syncthreads();

    int wv = t >> 6, l = t & 63;
    int lr = l & 15, lk = (l >> 4) * 8;

    f32x4 acc[8];
    #pragma unroll
    for (int i = 0; i < 8; ++i) acc[i] = (f32x4){0.f, 0.f, 0.f, 0.f};

    const _Float16* xrow = &xs[(wv * 16 + lr) * GPAD + lk];
    #pragma unroll
    for (int ks = 0; ks < 4; ++ks) {
        half8 a = *(const half8*)&xrow[ks * 32];
        #pragma unroll
        for (int f8 = 0; f8 < 8; ++f8) {
            half8 b = *(const half8*)&ws[(f8 * 16 + lr) * GPAD + ks * 32 + lk];
            acc[f8] = __builtin_amdgcn_mfma_f32_16x16x32_f16(a, b, acc[f8], 0, 0, 0);
        }
    }

    // epilogue: h fp16 stores + per-(node,head) alpha via 16-lane shfl reduce
    float asv[8], adv[8];
    #pragma unroll
    for (int f8 = 0; f8 < 8; ++f8) {
        asv[f8] = a_src[f8 * 16 + lr];
        adv[f8] = a_dst[f8 * 16 + lr];
    }
    #pragma unroll
    for (int r = 0; r < 4; ++r) {
        int n = n0 + wv * 16 + (l >> 4) * 4 + r;
        bool ok = (n < n_nodes);
        float ps[4] = {0.f, 0.f, 0.f, 0.f};
        float pd[4] = {0.f, 0.f, 0.f, 0.f};
        #pragma unroll
        for (int f8 = 0; f8 < 8; ++f8) {
            float v = acc[f8][r];
            if (ok) h[n * FEAT + f8 * 16 + lr] = __float2half(v);
            ps[f8 >> 1] += v * asv[f8];
            pd[f8 >> 1] += v * adv[f8];
        }
        #pragma unroll
        for (int m = 1; m <= 8; m <<= 1) {
            #pragma unroll
            for (int hd = 0; hd < 4; ++hd) {
                ps[hd] += __shfl_xor(ps[hd], m, 64);
                pd[hd] += __shfl_xor(pd[hd], m, 64);
            }
        }
        if (ok && lr == 0) {
            #pragma unroll
            for (int hd = 0; hd < 4; ++hd) {
                asrc_n[n * HEADS + hd] = ps[hd];
                adst_n[n * HEADS + hd] = pd[hd];
            }
        }
    }
}

// ---------------- per-destination-node softmax aggregation (unchanged from R11) ------

__global__ __launch_bounds__(256) void aggregate_kernel(
        const __half* __restrict__ h, const int* __restrict__ offsets,
        const int* __restrict__ col, const float* __restrict__ asrc_n,
        const float* __restrict__ adst_n, const float* __restrict__ bias,
        float* __restrict__ out, int n_nodes) {
    int wave = threadIdx.x >> 6;
    int lane = threadIdx.x & 63;
    int n = blockIdx.x * 4 + wave;
    if (n >= n_nodes) return;

    int head = lane >> 4;
    int lane2 = 2 * lane;
    int beg = offsets[n];
    int end = offsets[n + 1];
    float ad = adst_n[n * HEADS + head];

    float e_self = asrc_n[n * HEADS + head] + ad;
    e_self = e_self > 0.f ? e_self : NEG_SLOPE * e_self;
    float p = __expf(fminf(e_self, 60.f));
    float l = p;
    float2 hv = __half22float2(*(const __half2*)&h[n * FEAT + lane2]);
    float2 acc = make_float2(p * hv.x, p * hv.y);

    int j = beg;
    for (; j + 7 < end; j += 8) {
        int s[8];
        #pragma unroll
        for (int q = 0; q < 8; ++q) s[q] = col[j + q];
        float a[8];
        #pragma unroll
        for (int q = 0; q < 8; ++q) a[q] = asrc_n[s[q] * HEADS + head];
        __half2 hr[8];
        #pragma unroll
        for (int q = 0; q < 8; ++q) hr[q] = *(const __half2*)&h[s[q] * FEAT + lane2];
        #pragma unroll
        for (int q = 0; q < 8; ++q) {
            float e = a[q] + ad;
            e = e > 0.f ? e : NEG_SLOPE * e;
            float pe = __expf(fminf(e, 60.f));
            float2 hf = __half22float2(hr[q]);
            l += pe;
            acc.x += pe * hf.x;
            acc.y += pe * hf.y;
        }
    }
    for (; j + 3 < end; j += 4) {
        int s[4];
        #pragma unroll
        for (int q = 0; q < 4; ++q) s[q] = col[j + q];
        float a[4];
        #pragma unroll
        for (int q = 0; q < 4; ++q) a[q] = asrc_n[s[q] * HEADS + head];
        __half2 hr[4];
        #pragma unroll
        for (int q = 0; q < 4; ++q) hr[q] = *(const __half2*)&h[s[q] * FEAT + lane2];
        #pragma unroll
        for (int q = 0; q < 4; ++q) {
            float e = a[q] + ad;
            e = e > 0.f ? e : NEG_SLOPE * e;
            float pe = __expf(fminf(e, 60.f));
            float2 hf = __half22float2(hr[q]);
            l += pe;
            acc.x += pe * hf.x;
            acc.y += pe * hf.y;
        }
    }
    for (; j < end; ++j) {
        int s = col[j];
        float a = asrc_n[s * HEADS + head];
        float2 hs = __half22float2(*(const __half2*)&h[s * FEAT + lane2]);
        float e = a + ad;
        e = e > 0.f ? e : NEG_SLOPE * e;
        float pe = __expf(fminf(e, 60.f));
        l += pe;
        acc.x += pe * hs.x;
        acc.y += pe * hs.y;
    }

    float inv = 1.f / l;
    float2 bv = *(const float2*)&bias[lane2];
    float ox = acc.x * inv + bv.x;
    float oy = acc.y * inv + bv.y;
    float2 o = make_float2(ox > 0.f ? ox : 0.f, oy > 0.f ? oy : 0.f);
    *(float2*)&out[n * FEAT + lane2] = o;
}

// ---------------- launch ----------------

static inline size_t align_up(size_t v, size_t a) { return (v + a - 1) & ~(a - 1); }

extern "C" void kernel_launch(void* const* d_in, const int* in_sizes, int n_in,
                              void* d_out, int out_size, void* d_ws, size_t ws_size,
                              hipStream_t stream) {
    const float* x   = (const float*)d_in[0];
    const int*   ei  = (const int*)d_in[1];
    const float* W1  = (const float*)d_in[2];
    const float* as1 = (const float*)d_in[3];
    const float* ad1 = (const float*)d_in[4];
    const float* b1  = (const float*)d_in[5];
    const float* W2  = (const float*)d_in[6];
    const float* as2 = (const float*)d_in[7];
    const float* ad2 = (const float*)d_in[8];
    const float* b2  = (const float*)d_in[9];

    int N = in_sizes[0] / FEAT;
    int E = in_sizes[1] / 2;
    const int* src_idx = ei;
    const int* dst_idx = ei + E;

    int nsb = (N + SCAN_B - 1) / SCAN_B;

    char* p = (char*)d_ws;
    auto alloc = [&](size_t bytes) {
        char* r = p;
        p += align_up(bytes, 256);
        return r;
    };
    int*    deg      = (int*)alloc((size_t)N * 4);
    int*    offsets  = (int*)alloc((size_t)(N + 1) * 4);
    int*    cursor   = (int*)alloc((size_t)N * 4);
    int*    col      = (int*)alloc((size_t)E * 4);
    int*    scanout  = (int*)alloc((size_t)N * 4);
    int*    blocksum = (int*)alloc((size_t)nsb * 4);
    __half* h        = (__half*)alloc((size_t)N * FEAT * 2);
    __half* wt1      = (__half*)alloc((size_t)FEAT * FEAT * 2);
    __half* wt2      = (__half*)alloc((size_t)FEAT * FEAT * 2);
    float*  asn      = (float*)alloc((size_t)N * HEADS * 4);
    float*  adn      = (float*)alloc((size_t)N * HEADS * 4);
    float*  buf1     = (float*)d_out;  // layer-1 output staged in d_out, overwritten by layer 2

    // CSR build (graph shared by both layers) + W transposes
    hipMemsetAsync(deg, 0, (size_t)N * 4, stream);
    count_kernel<<<1024, 256, 0, stream>>>(dst_idx, deg, E);
    wtrans_kernel<<<8, 256, 0, stream>>>(W1, wt1);
    wtrans_kernel<<<8, 256, 0, stream>>>(W2, wt2);
    scan_local_kernel<<<nsb, SCAN_B, 0, stream>>>(deg, scanout, blocksum, N);
    scan_sums_kernel<<<1, SCAN_B, 0, stream>>>(blocksum, nsb);
    scan_add_kernel<<<(N + 255) / 256, 256, 0, stream>>>(scanout, blocksum, offsets, N);
    hipMemcpyAsync(cursor, offsets, (size_t)N * 4, hipMemcpyDeviceToDevice, stream);
    scatter_kernel<<<1024, 256, 0, stream>>>(src_idx, dst_idx, cursor, col, E);

    int gemm_grid = (N + 63) / 64;
    int agg_grid = (N + 3) / 4;

    // layer 1
    gemm_alpha_kernel<<<gemm_grid, 256, 0, stream>>>(x, wt1, as1, ad1, h, asn, adn, N);
    aggregate_kernel<<<agg_grid, 256, 0, stream>>>(h, offsets, col, asn, adn, b1, buf1, N);

    // layer 2 (input = buf1 in d_out; final output overwrites d_out)
    gemm_alpha_kernel<<<gemm_grid, 256, 0, stream>>>(buf1, wt2, as2, ad2, h, asn, adn, N);
    aggregate_kernel<<<agg_grid, 256, 0, stream>>>(h, offsets, col, asn, adn, b2, (float*)d_out, N);
}